// Round 1
// baseline (2425.925 us; speedup 1.0000x reference)
//
#include <hip/hip_runtime.h>
#include <math.h>

#define Bn 64
#define Tn 2048
#define Hn 256
#define NIc 4
#define NAc 2

constexpr float LEAK    = 0.5f;     // 1 - 1/TAU
constexpr float NEGDIAG = -0.5f;    // -1/TAU
constexpr float CLAMP_V = 1000.0f;
constexpr float EPS_V   = 1e-4f;

// ---------------------------------------------------------------------------
// K1: u[r, j] = sum_k relu( inp8[r] . W1[k] + b1[k] ) * Wih[j][k]
//     r = t*B + b (row of the (T,B,H) tensor), 64 rows/block, j = threadIdx.
// ---------------------------------------------------------------------------
__global__ __launch_bounds__(256) void k_u(
    const float* __restrict__ reward, const float* __restrict__ state,
    const float* __restrict__ last_action, const float* __restrict__ W1,
    const float* __restrict__ b1, const float* __restrict__ Wih,
    float* __restrict__ u)
{
  __shared__ float inp_s[64][8];
  __shared__ float w1_s[256][8];
  __shared__ float b1_s[256];
  __shared__ __align__(16) float x_s[32][68];   // [kk][rr], padded
  __shared__ float w_s[32][257];                // [kk][j],  padded
  const int tid = threadIdx.x;
  const int r0  = blockIdx.x * 64;

  for (int idx = tid; idx < 2048; idx += 256) ((float*)w1_s)[idx] = W1[idx];
  b1_s[tid] = b1[tid];
  for (int idx = tid; idx < 512; idx += 256) {
    int rr = idx >> 3, i = idx & 7;
    int r = r0 + rr; int b = r & (Bn - 1); int t = r >> 6;
    long base = (long)b * Tn + t;
    float v;
    if (i < NAc)            v = reward[base * NAc + i];
    else if (i < NAc + NIc) v = state[base * NIc + (i - NAc)];
    else                    v = last_action[base * NAc + (i - NAc - NIc)];
    inp_s[rr][i] = v;
  }

  float acc[64];
  #pragma unroll
  for (int rr = 0; rr < 64; ++rr) acc[rr] = 0.f;

  for (int c = 0; c < 8; ++c) {
    const int k0 = c * 32;
    __syncthreads();
    for (int idx = tid; idx < 8192; idx += 256) {      // Wih chunk, transposed
      int j = idx >> 5, kk = idx & 31;
      w_s[kk][j] = Wih[j * 256 + k0 + kk];
    }
    for (int idx = tid; idx < 2048; idx += 256) {      // x chunk on the fly
      int kk = idx & 31, rr = idx >> 5;
      int k = k0 + kk;
      float s = b1_s[k];
      #pragma unroll
      for (int i = 0; i < 8; ++i) s = fmaf(inp_s[rr][i], w1_s[k][i], s);
      x_s[kk][rr] = fmaxf(s, 0.f);
    }
    __syncthreads();
    #pragma unroll
    for (int kk = 0; kk < 32; ++kk) {
      float wv = w_s[kk][tid];
      const float4* xp = reinterpret_cast<const float4*>(&x_s[kk][0]);
      #pragma unroll
      for (int q = 0; q < 16; ++q) {
        float4 xv = xp[q];
        acc[4*q+0] = fmaf(xv.x, wv, acc[4*q+0]);
        acc[4*q+1] = fmaf(xv.y, wv, acc[4*q+1]);
        acc[4*q+2] = fmaf(xv.z, wv, acc[4*q+2]);
        acc[4*q+3] = fmaf(xv.w, wv, acc[4*q+3]);
      }
    }
  }
  for (int rr = 0; rr < 64; ++rr)
    u[(long)(r0 + rr) * Hn + tid] = acc[rr];
}

// ---------------------------------------------------------------------------
// K2: sequential scan. 1 block per batch row, 512 threads: thread (j, half)
// holds Whh[j][half*128 .. +127] in 128 VGPRs. rh broadcast via LDS.
// ys overwrites ubuf in place. Writes hidden_out at the end.
// ---------------------------------------------------------------------------
__global__ __launch_bounds__(512) void k_scan(
    const float* __restrict__ Whh_raw, const float* __restrict__ hidden_in,
    float* __restrict__ ubuf, float* __restrict__ out)
{
  __shared__ __align__(16) float rh[2][256];
  __shared__ float part[256];
  const int tid  = threadIdx.x;
  const int j    = tid & 255;
  const int half = tid >> 8;
  const int b    = blockIdx.x;
  const int kbase = half * 128;

  float w[128];
  #pragma unroll
  for (int kk = 0; kk < 128; ++kk) {
    int k = kbase + kk;
    float v = Whh_raw[j * 256 + k];
    w[kk] = (k == j) ? NEGDIAG : v;
  }

  float h = 0.f, u_cur = 0.f;
  if (half == 0) {
    h = hidden_in[b * Hn + j];
    u_cur = ubuf[(long)b * Hn + j];      // t = 0
  }

  for (int t = 0; t < Tn; ++t) {
    const int p = t & 1;
    if (half == 0) rh[p][j] = fmaxf(h, 0.f);
    __syncthreads();
    float u_nxt = 0.f;
    if (half == 0 && t + 1 < Tn)
      u_nxt = ubuf[((long)(t + 1) * Bn + b) * Hn + j];

    float a0 = 0.f, a1 = 0.f, a2 = 0.f, a3 = 0.f;
    const float4* rp = reinterpret_cast<const float4*>(&rh[p][kbase]);
    #pragma unroll
    for (int q = 0; q < 32; ++q) {
      float4 r4 = rp[q];
      a0 = fmaf(r4.x, w[4*q+0], a0);
      a1 = fmaf(r4.y, w[4*q+1], a1);
      a2 = fmaf(r4.z, w[4*q+2], a2);
      a3 = fmaf(r4.w, w[4*q+3], a3);
    }
    float s = (a0 + a1) + (a2 + a3);
    if (half == 1) part[j] = s;
    __syncthreads();
    if (half == 0) {
      float hn = fmaf(LEAK, h, u_cur) + s + part[j];
      hn = fminf(fmaxf(hn, -CLAMP_V), CLAMP_V);
      ubuf[((long)t * Bn + b) * Hn + j] = hn;   // ys in place
      h = hn; u_cur = u_nxt;
    }
  }
  if (half == 0) out[(long)Bn * Tn * NAc + b * Hn + j] = h;
}

// ---------------------------------------------------------------------------
// K3: v = relu(ys @ W2^T + b2); y = v @ W3^T + b3; softmax/mix epilogue.
// Same tiling as K1; cross-thread dot with W3 via wave shuffles.
// ---------------------------------------------------------------------------
__global__ __launch_bounds__(256) void k_out(
    const float* __restrict__ ys, const float* __restrict__ W2,
    const float* __restrict__ b2, const float* __restrict__ W3,
    const float* __restrict__ b3, const float* __restrict__ Qs,
    const float* __restrict__ reward, const float* __restrict__ mix_w,
    float* __restrict__ out)
{
  __shared__ __align__(16) float a_s[32][68];
  __shared__ float w_s[32][257];
  __shared__ float part_s[4][64][2];
  const int tid = threadIdx.x;
  const int r0  = blockIdx.x * 64;
  const float b2v = b2[tid];
  const float w3a = W3[tid];
  const float w3b = W3[256 + tid];

  float acc[64];
  #pragma unroll
  for (int rr = 0; rr < 64; ++rr) acc[rr] = 0.f;

  for (int c = 0; c < 8; ++c) {
    const int k0 = c * 32;
    __syncthreads();
    for (int idx = tid; idx < 8192; idx += 256) {
      int jj = idx >> 5, kk = idx & 31;
      w_s[kk][jj] = W2[jj * 256 + k0 + kk];
    }
    for (int idx = tid; idx < 2048; idx += 256) {
      int kk = idx & 31, rr = idx >> 5;
      a_s[kk][rr] = ys[(long)(r0 + rr) * Hn + k0 + kk];
    }
    __syncthreads();
    #pragma unroll
    for (int kk = 0; kk < 32; ++kk) {
      float wv = w_s[kk][tid];
      const float4* xp = reinterpret_cast<const float4*>(&a_s[kk][0]);
      #pragma unroll
      for (int q = 0; q < 16; ++q) {
        float4 xv = xp[q];
        acc[4*q+0] = fmaf(xv.x, wv, acc[4*q+0]);
        acc[4*q+1] = fmaf(xv.y, wv, acc[4*q+1]);
        acc[4*q+2] = fmaf(xv.z, wv, acc[4*q+2]);
        acc[4*q+3] = fmaf(xv.w, wv, acc[4*q+3]);
      }
    }
  }

  const int lane = tid & 63, wid = tid >> 6;
  for (int rr = 0; rr < 64; ++rr) {
    float v  = fmaxf(acc[rr] + b2v, 0.f);
    float p0 = v * w3a;
    float p1 = v * w3b;
    #pragma unroll
    for (int off = 32; off; off >>= 1) {
      p0 += __shfl_xor(p0, off);
      p1 += __shfl_xor(p1, off);
    }
    if (lane == 0) { part_s[wid][rr][0] = p0; part_s[wid][rr][1] = p1; }
  }
  __syncthreads();

  if (tid < 128) {
    int rr = tid >> 1, a = tid & 1;
    float y = part_s[0][rr][a] + part_s[1][rr][a]
            + part_s[2][rr][a] + part_s[3][rr][a] + b3[a];
    int r = r0 + rr;
    int t = r >> 6, b = r & (Bn - 1);
    float z = (y == 0.f) ? EPS_V : 0.f;

    float y2 = __shfl_xor(y, 1);
    float m  = fmaxf(y, y2);
    float e  = expf(y - m), e2 = expf(y2 - m);
    float sp = e / (e + e2);

    long qi = ((long)b * Tn + t) * NAc + a;
    float qv = Qs[qi];
    float q2 = __shfl_xor(qv, 1);
    float mq = fmaxf(qv, q2);
    float eq = expf(qv - mq), eq2 = expf(q2 - mq);
    float sq = eq / (eq + eq2);

    int ri = (int)reward[((long)b * Tn + t) * NAc];
    float m0 = fminf(fmaxf(mix_w[ri * 2 + 0], -1.f), 1.f);
    float m1 = fminf(fmaxf(mix_w[ri * 2 + 1], -1.f), 1.f);
    float den = fabsf(m0) + fabsf(m1);
    float sel0 = m0 / den, sel1 = m1 / den;

    float mixed = sel0 * logf(sp + z) + sel1 * logf(sq + z);
    out[((long)b * Tn + t) * NAc + a] = expf(mixed);
  }
}

// ---------------------------------------------------------------------------
extern "C" void kernel_launch(void* const* d_in, const int* in_sizes, int n_in,
                              void* d_out, int out_size, void* d_ws, size_t ws_size,
                              hipStream_t stream)
{
  const float* state       = (const float*)d_in[0];
  const float* last_action = (const float*)d_in[1];
  const float* reward      = (const float*)d_in[2];
  const float* hidden_in   = (const float*)d_in[3];
  const float* W1          = (const float*)d_in[4];
  const float* b1          = (const float*)d_in[5];
  const float* Wih         = (const float*)d_in[6];
  const float* Whh_raw     = (const float*)d_in[7];
  const float* W2          = (const float*)d_in[8];
  const float* b2          = (const float*)d_in[9];
  const float* W3          = (const float*)d_in[10];
  const float* b3          = (const float*)d_in[11];
  const float* Qs          = (const float*)d_in[12];
  const float* mix_w       = (const float*)d_in[13];
  float* out = (float*)d_out;
  float* u   = (float*)d_ws;   // (T*B, H) fp32 = 128 MiB; ys overwrites in place

  const int nrows = Tn * Bn;               // 131072
  k_u   <<<nrows / 64, 256, 0, stream>>>(reward, state, last_action, W1, b1, Wih, u);
  k_scan<<<Bn,        512, 0, stream>>>(Whh_raw, hidden_in, u, out);
  k_out <<<nrows / 64, 256, 0, stream>>>(u, W2, b2, W3, b3, Qs, reward, mix_w, out);
}